// Round 1
// baseline (920.489 us; speedup 1.0000x reference)
//
#include <hip/hip_runtime.h>

#define NEG_SLOPE 0.2f

// ---------------------------------------------------------------------------
// GEMM + attention projections:
//   H[r,:] = X[r,:] @ W   (128x128, W staged in LDS)
//   AL[r]  = (al_src_h0, al_src_h1, al_dst_h0, al_dst_h1)
// One wave per row; lane i owns output channels {2i, 2i+1} (head = i>>5).
// ---------------------------------------------------------------------------
__global__ __launch_bounds__(256) void gemm_al_kernel(
    const float* __restrict__ X, const float* __restrict__ W,
    const float* __restrict__ asrc, const float* __restrict__ adst,
    float* __restrict__ H, float* __restrict__ AL, int N, int rows_per_wave)
{
    __shared__ float Wl[128 * 128];   // 64 KiB
    __shared__ float xbuf[4][128];    // per-wave x row staging

    const int t = threadIdx.x;
    const float4* W4 = (const float4*)W;
    float4* Wl4 = (float4*)Wl;
#pragma unroll
    for (int i = 0; i < 16; i++) Wl4[t + i * 256] = W4[t + i * 256];
    __syncthreads();

    const int wave = t >> 6, lane = t & 63;
    const float as0 = asrc[2 * lane], as1 = asrc[2 * lane + 1];
    const float ad0 = adst[2 * lane], ad1 = adst[2 * lane + 1];

    const int base = blockIdx.x * (4 * rows_per_wave) + wave * rows_per_wave;
    for (int i = 0; i < rows_per_wave; i++) {
        const int r = base + i;
        if (r >= N) break;
        float2 xv = ((const float2*)X)[(size_t)r * 64 + lane];
        ((float2*)xbuf[wave])[lane] = xv;   // same-wave write->read; compiler orders via lgkmcnt

        float acc0 = 0.f, acc1 = 0.f;
#pragma unroll 16
        for (int k = 0; k < 128; k++) {
            const float xk = xbuf[wave][k];             // broadcast read
            const float2 wv = ((const float2*)(Wl + k * 128))[lane]; // 2-way bank alias: free
            acc0 = fmaf(xk, wv.x, acc0);
            acc1 = fmaf(xk, wv.y, acc1);
        }
        ((float2*)H)[(size_t)r * 64 + lane] = make_float2(acc0, acc1);

        float ps = acc0 * as0 + acc1 * as1;
        float pd = acc0 * ad0 + acc1 * ad1;
#pragma unroll
        for (int off = 16; off > 0; off >>= 1) {   // reduce within each 32-lane head group
            ps += __shfl_xor(ps, off, 64);
            pd += __shfl_xor(pd, off, 64);
        }
        if (lane == 0)       { AL[(size_t)r * 4 + 0] = ps; AL[(size_t)r * 4 + 2] = pd; }
        else if (lane == 32) { AL[(size_t)r * 4 + 1] = ps; AL[(size_t)r * 4 + 3] = pd; }
    }
}

// ---------------------------------------------------------------------------
// CSR build: count -> scan (3 kernels) -> scatter. Self-loops appended.
// ---------------------------------------------------------------------------
__global__ void count_kernel(const int* __restrict__ edst, int* __restrict__ cnt,
                             int E, int N)
{
    int i = blockIdx.x * 256 + threadIdx.x;
    if (i < E)            atomicAdd(&cnt[edst[i]], 1);
    else if (i < E + N)   atomicAdd(&cnt[i - E], 1);   // self loop
}

#define SCAN_B 1024
__global__ void scan1_kernel(const int* __restrict__ cnt, int* __restrict__ incl,
                             int* __restrict__ bsum, int N)
{
    __shared__ int sm[SCAN_B];
    const int t = threadIdx.x;
    const int i = blockIdx.x * SCAN_B + t;
    int v = (i < N) ? cnt[i] : 0;
    sm[t] = v;
    __syncthreads();
    for (int off = 1; off < SCAN_B; off <<= 1) {
        int x = (t >= off) ? sm[t - off] : 0;
        __syncthreads();
        sm[t] += x;
        __syncthreads();
    }
    if (i < N) incl[i] = sm[t];
    if (t == SCAN_B - 1) bsum[blockIdx.x] = sm[t];
}

__global__ void scan2_kernel(int* __restrict__ bsum, int B)
{
    __shared__ int sm[1024];
    const int t = threadIdx.x;
    int v = (t < B) ? bsum[t] : 0;
    sm[t] = v;
    __syncthreads();
    for (int off = 1; off < 1024; off <<= 1) {
        int x = (t >= off) ? sm[t - off] : 0;
        __syncthreads();
        sm[t] += x;
        __syncthreads();
    }
    if (t < B) bsum[t] = sm[t] - v;   // exclusive
}

__global__ void scan3_kernel(int* __restrict__ indptr /*in: incl, out: excl*/,
                             const int* __restrict__ cnt, const int* __restrict__ bsum,
                             int* __restrict__ cursor, int N, int Etot)
{
    const int i = blockIdx.x * SCAN_B + threadIdx.x;
    if (i < N) {
        int v = indptr[i] - cnt[i] + bsum[blockIdx.x];
        indptr[i] = v;
        cursor[i] = v;
    }
    if (i == N) indptr[N] = Etot;
}

__global__ void scatter_kernel(const int* __restrict__ esrc, const int* __restrict__ edst,
                               int* __restrict__ cursor, int* __restrict__ ssrc,
                               int E, int N)
{
    int i = blockIdx.x * 256 + threadIdx.x;
    int s, d;
    if (i < E)          { s = esrc[i]; d = edst[i]; }
    else if (i < E + N) { s = d = i - E; }
    else return;
    int pos = atomicAdd(&cursor[d], 1);
    ssrc[pos] = s;
}

// ---------------------------------------------------------------------------
// Per-destination-node online-softmax aggregation. One wave per node.
// lane i owns channels {2i,2i+1}; head = lane>>5.
// mode 0: layer1 -> out[n,128] = ELU(acc/s + b)     (concat heads)
// mode 1: layer2 -> out[n,64]  = mean_h(acc/s) + b  (head mean)
// ---------------------------------------------------------------------------
__global__ __launch_bounds__(256) void aggregate_kernel(
    const float* __restrict__ H, const float* __restrict__ AL,
    const int* __restrict__ indptr, const int* __restrict__ ssrc,
    const float* __restrict__ bias, float* __restrict__ out,
    int N, int mode)
{
    const int w = (blockIdx.x * blockDim.x + threadIdx.x) >> 6;
    const int lane = threadIdx.x & 63;
    if (w >= N) return;
    const int n = w;

    const int beg = indptr[n], end = indptr[n + 1];
    const float2 ald = *(const float2*)(AL + (size_t)n * 4 + 2);
    const int head = lane >> 5;
    const float aldh = head ? ald.y : ald.x;

    float m = -__builtin_inff(), s = 0.f;
    float ax = 0.f, ay = 0.f;

    // 1-deep software prefetch pipeline
    int src = ssrc[beg];
    float2 als = *(const float2*)(AL + (size_t)src * 4);
    float2 hv  = *(const float2*)(H + (size_t)src * 128 + 2 * lane);

    for (int j = beg; j < end; j++) {
        float2 als_n = make_float2(0.f, 0.f), hv_n = make_float2(0.f, 0.f);
        if (j + 1 < end) {
            const int s2 = ssrc[j + 1];
            als_n = *(const float2*)(AL + (size_t)s2 * 4);
            hv_n  = *(const float2*)(H + (size_t)s2 * 128 + 2 * lane);
        }
        float e = (head ? als.y : als.x) + aldh;
        e = (e >= 0.f) ? e : NEG_SLOPE * e;
        const float mn = fmaxf(m, e);
        const float c = __expf(m - mn);   // first iter: exp(-inf) = 0
        const float p = __expf(e - mn);
        s  = s * c + p;
        ax = ax * c + p * hv.x;
        ay = ay * c + p * hv.y;
        m = mn;
        als = als_n; hv = hv_n;
    }

    const float inv = 1.f / s;            // s >= exp(0) from self loop
    float o0 = ax * inv, o1 = ay * inv;

    if (mode == 0) {
        o0 += bias[2 * lane]; o1 += bias[2 * lane + 1];
        o0 = (o0 > 0.f) ? o0 : (__expf(o0) - 1.f);   // ELU
        o1 = (o1 > 0.f) ? o1 : (__expf(o1) - 1.f);
        ((float2*)out)[(size_t)n * 64 + lane] = make_float2(o0, o1);
    } else {
        const float p0 = __shfl_xor(o0, 32, 64);
        const float p1 = __shfl_xor(o1, 32, 64);
        if (lane < 32) {
            const float r0 = 0.5f * (o0 + p0) + bias[2 * lane];
            const float r1 = 0.5f * (o1 + p1) + bias[2 * lane + 1];
            ((float2*)out)[(size_t)n * 32 + lane] = make_float2(r0, r1);
        }
    }
}

// ---------------------------------------------------------------------------
extern "C" void kernel_launch(void* const* d_in, const int* in_sizes, int n_in,
                              void* d_out, int out_size, void* d_ws, size_t ws_size,
                              hipStream_t stream)
{
    const float* x   = (const float*)d_in[0];
    const int*   eix = (const int*)d_in[1];   // [2, E] int32
    const float* W1  = (const float*)d_in[2];
    const float* as1 = (const float*)d_in[3];
    const float* ad1 = (const float*)d_in[4];
    const float* b1  = (const float*)d_in[5];
    const float* W2  = (const float*)d_in[6];
    const float* as2 = (const float*)d_in[7];
    const float* ad2 = (const float*)d_in[8];
    const float* b2  = (const float*)d_in[9];
    float* out = (float*)d_out;

    const int N = in_sizes[0] / 128;
    const int E = in_sizes[1] / 2;
    const int Etot = E + N;
    const int* esrc = eix;
    const int* edst = eix + E;

    // workspace layout (~113 MB)
    char* p = (char*)d_ws;
    float* h      = (float*)p; p += (size_t)N * 128 * 4;
    float* y1     = (float*)p; p += (size_t)N * 128 * 4;
    float* al     = (float*)p; p += (size_t)N * 4 * 4;
    int*   cnt    = (int*)p;   p += (size_t)N * 4;
    int*   indptr = (int*)p;   p += (size_t)(N + 1) * 4;
    int*   cursor = (int*)p;   p += (size_t)N * 4;
    int*   bsum   = (int*)p;   p += 1024 * 4;
    int*   ssrc   = (int*)p;   p += (size_t)Etot * 4;

    hipMemsetAsync(cnt, 0, (size_t)N * 4, stream);

    // --- CSR by destination (shared by both layers) ---
    {
        const int eblocks = (Etot + 255) / 256;
        count_kernel<<<eblocks, 256, 0, stream>>>(edst, cnt, E, N);
        const int B = (N + SCAN_B - 1) / SCAN_B;
        scan1_kernel<<<B, SCAN_B, 0, stream>>>(cnt, indptr, bsum, N);
        scan2_kernel<<<1, 1024, 0, stream>>>(bsum, B);
        scan3_kernel<<<B, SCAN_B, 0, stream>>>(indptr, cnt, bsum, cursor, N, Etot);
        scatter_kernel<<<eblocks, 256, 0, stream>>>(esrc, edst, cursor, ssrc, E, N);
    }

    const int ggrid = (N + 31) / 32;                       // 32 rows/block
    const int ablocks = (int)(((size_t)N * 64 + 255) / 256); // 1 wave per node

    // --- Layer 1: h = x@W1, aggregate -> y1 = ELU(gat + b1) ---
    gemm_al_kernel<<<ggrid, 256, 0, stream>>>(x, W1, as1, ad1, h, al, N, 8);
    aggregate_kernel<<<ablocks, 256, 0, stream>>>(h, al, indptr, ssrc, b1, y1, N, 0);

    // --- Layer 2: h = y1@W2 (reuse h/al), aggregate -> out (head mean + b2) ---
    gemm_al_kernel<<<ggrid, 256, 0, stream>>>(y1, W2, as2, ad2, h, al, N, 8);
    aggregate_kernel<<<ablocks, 256, 0, stream>>>(h, al, indptr, ssrc, b2, out, N, 1);
}

// Round 2
// 693.953 us; speedup vs baseline: 1.3264x; 1.3264x over previous
//
#include <hip/hip_runtime.h>

#define NEG_SLOPE 0.2f

// ---------------------------------------------------------------------------
// float<->ordered-uint encoding for atomicMax on floats
// ---------------------------------------------------------------------------
__device__ inline unsigned enc_max(float f) {
    unsigned b = __float_as_uint(f);
    return (b & 0x80000000u) ? ~b : (b | 0x80000000u);
}
__device__ inline float dec_max(unsigned k) {
    return (k & 0x80000000u) ? __uint_as_float(k ^ 0x80000000u)
                             : __uint_as_float(~k);
}

// ---------------------------------------------------------------------------
// GEMM + attention projections:
//   H[r,:] = X[r,:] @ W   (128x128, W staged in LDS)
//   AL[r]  = (al_src_h0, al_src_h1, al_dst_h0, al_dst_h1)
// 512 threads = 8 waves; each wave does 16 rows in 4-row register blocks.
// lane i owns output channels {2i, 2i+1} (head = i>>5).
// LDS = 64KB W + 16KB xbuf = 80KB -> 2 blocks/CU -> 8 waves/SIMD.
// ---------------------------------------------------------------------------
__device__ inline void row_out(int r, int N, int lane, float A0, float A1,
                               float as0, float as1, float ad0, float ad1,
                               float* __restrict__ H, float* __restrict__ AL)
{
    if (r >= N) return;
    ((float2*)H)[(size_t)r * 64 + lane] = make_float2(A0, A1);
    float ps = A0 * as0 + A1 * as1;
    float pd = A0 * ad0 + A1 * ad1;
#pragma unroll
    for (int off = 16; off > 0; off >>= 1) {   // reduce within each 32-lane head
        ps += __shfl_xor(ps, off, 64);
        pd += __shfl_xor(pd, off, 64);
    }
    if (lane == 0)       { AL[(size_t)r * 4 + 0] = ps; AL[(size_t)r * 4 + 2] = pd; }
    else if (lane == 32) { AL[(size_t)r * 4 + 1] = ps; AL[(size_t)r * 4 + 3] = pd; }
}

__global__ __launch_bounds__(512) void gemm_al_kernel(
    const float* __restrict__ X, const float* __restrict__ W,
    const float* __restrict__ asrc, const float* __restrict__ adst,
    float* __restrict__ H, float* __restrict__ AL, int N)
{
    __shared__ float Wl[128 * 128];   // 64 KiB
    __shared__ float xb[8][4][128];   // 16 KiB: per-wave 4-row x staging

    const int t = threadIdx.x;
    const float4* W4 = (const float4*)W;
    float4* Wl4 = (float4*)Wl;
#pragma unroll
    for (int i = 0; i < 8; i++) Wl4[t + i * 512] = W4[t + i * 512];
    __syncthreads();

    const int wave = t >> 6, lane = t & 63;
    const float as0 = asrc[2 * lane], as1 = asrc[2 * lane + 1];
    const float ad0 = adst[2 * lane], ad1 = adst[2 * lane + 1];
    const float2* X2 = (const float2*)X;

    const int base = (blockIdx.x * 8 + wave) * 16;
    for (int r0 = base; r0 < base + 16; r0 += 4) {
#pragma unroll
        for (int rb = 0; rb < 4; rb++) {
            const int r = r0 + rb;
            float2 xv = make_float2(0.f, 0.f);
            if (r < N) xv = X2[(size_t)r * 64 + lane];
            ((float2*)xb[wave][rb])[lane] = xv;   // same-wave write->read (lgkmcnt)
        }
        float a00 = 0.f, a01 = 0.f, a10 = 0.f, a11 = 0.f;
        float a20 = 0.f, a21 = 0.f, a30 = 0.f, a31 = 0.f;
#pragma unroll 16
        for (int k = 0; k < 128; k++) {
            const float2 wv = ((const float2*)(Wl + k * 128))[lane];
            const float x0 = xb[wave][0][k];
            const float x1 = xb[wave][1][k];
            const float x2 = xb[wave][2][k];
            const float x3 = xb[wave][3][k];
            a00 = fmaf(x0, wv.x, a00); a01 = fmaf(x0, wv.y, a01);
            a10 = fmaf(x1, wv.x, a10); a11 = fmaf(x1, wv.y, a11);
            a20 = fmaf(x2, wv.x, a20); a21 = fmaf(x2, wv.y, a21);
            a30 = fmaf(x3, wv.x, a30); a31 = fmaf(x3, wv.y, a31);
        }
        row_out(r0 + 0, N, lane, a00, a01, as0, as1, ad0, ad1, H, AL);
        row_out(r0 + 1, N, lane, a10, a11, as0, as1, ad0, ad1, H, AL);
        row_out(r0 + 2, N, lane, a20, a21, as0, as1, ad0, ad1, H, AL);
        row_out(r0 + 3, N, lane, a30, a31, as0, as1, ad0, ad1, H, AL);
    }
}

// ---------------------------------------------------------------------------
// Global max of al_src per head (upper bound for softmax shift)
// ---------------------------------------------------------------------------
__global__ void almax_kernel(const float* __restrict__ AL,
                             unsigned* __restrict__ ub, int N)
{
    float m0 = -__builtin_inff(), m1 = -__builtin_inff();
    for (int i = blockIdx.x * 256 + threadIdx.x; i < N; i += gridDim.x * 256) {
        m0 = fmaxf(m0, AL[(size_t)i * 4 + 0]);
        m1 = fmaxf(m1, AL[(size_t)i * 4 + 1]);
    }
#pragma unroll
    for (int off = 32; off > 0; off >>= 1) {
        m0 = fmaxf(m0, __shfl_xor(m0, off, 64));
        m1 = fmaxf(m1, __shfl_xor(m1, off, 64));
    }
    if ((threadIdx.x & 63) == 0) {
        atomicMax(&ub[0], enc_max(m0));
        atomicMax(&ub[1], enc_max(m1));
    }
}

// ---------------------------------------------------------------------------
// CSR build: count -> scan (3 kernels) -> scatter. Self-loops appended.
// ---------------------------------------------------------------------------
__global__ void count_kernel(const int* __restrict__ edst, int* __restrict__ cnt,
                             int E, int N)
{
    int i = blockIdx.x * 256 + threadIdx.x;
    if (i < E)            atomicAdd(&cnt[edst[i]], 1);
    else if (i < E + N)   atomicAdd(&cnt[i - E], 1);   // self loop
}

#define SCAN_B 1024
__global__ void scan1_kernel(const int* __restrict__ cnt, int* __restrict__ incl,
                             int* __restrict__ bsum, int N)
{
    __shared__ int sm[SCAN_B];
    const int t = threadIdx.x;
    const int i = blockIdx.x * SCAN_B + t;
    int v = (i < N) ? cnt[i] : 0;
    sm[t] = v;
    __syncthreads();
    for (int off = 1; off < SCAN_B; off <<= 1) {
        int x = (t >= off) ? sm[t - off] : 0;
        __syncthreads();
        sm[t] += x;
        __syncthreads();
    }
    if (i < N) incl[i] = sm[t];
    if (t == SCAN_B - 1) bsum[blockIdx.x] = sm[t];
}

__global__ void scan2_kernel(int* __restrict__ bsum, int B)
{
    __shared__ int sm[1024];
    const int t = threadIdx.x;
    int v = (t < B) ? bsum[t] : 0;
    sm[t] = v;
    __syncthreads();
    for (int off = 1; off < 1024; off <<= 1) {
        int x = (t >= off) ? sm[t - off] : 0;
        __syncthreads();
        sm[t] += x;
        __syncthreads();
    }
    if (t < B) bsum[t] = sm[t] - v;   // exclusive
}

__global__ void scan3_kernel(int* __restrict__ indptr /*in: incl, out: excl*/,
                             const int* __restrict__ cnt, const int* __restrict__ bsum,
                             int* __restrict__ cursor, int N, int Etot)
{
    const int i = blockIdx.x * SCAN_B + threadIdx.x;
    if (i < N) {
        int v = indptr[i] - cnt[i] + bsum[blockIdx.x];
        indptr[i] = v;
        cursor[i] = v;
    }
    if (i == N) indptr[N] = Etot;
}

__global__ void scatter_kernel(const int* __restrict__ esrc, const int* __restrict__ edst,
                               int* __restrict__ cursor, int* __restrict__ ssrc,
                               int E, int N)
{
    int i = blockIdx.x * 256 + threadIdx.x;
    int s, d;
    if (i < E)          { s = esrc[i]; d = edst[i]; }
    else if (i < E + N) { s = d = i - E; }
    else return;
    int pos = atomicAdd(&cursor[d], 1);
    ssrc[pos] = s;
}

// ---------------------------------------------------------------------------
// Per-destination aggregation, shifted softmax (no online rescale).
// One wave per node; lane i owns channels {2i,2i+1}; head = lane>>5.
// 3-stage pipeline over 4-edge blocks: ssrc(j+8) | AL,h(j+4) | compute(j).
// mode 0: out[n,128] = ELU(acc/s + b)    mode 1: out[n,64] = mean_h(acc/s)+b
// ---------------------------------------------------------------------------
__global__ __launch_bounds__(256) void aggregate_kernel(
    const float* __restrict__ H, const float* __restrict__ AL,
    const int* __restrict__ indptr, const int* __restrict__ ssrc,
    const unsigned* __restrict__ ubenc, const float* __restrict__ bias,
    float* __restrict__ out, int N, int mode)
{
    const int w = (blockIdx.x * blockDim.x + threadIdx.x) >> 6;
    const int lane = threadIdx.x & 63;
    if (w >= N) return;
    const int n = w;

    const int beg = indptr[n], end = indptr[n + 1];
    const int head = lane >> 5;
    const float ald = AL[(size_t)n * 4 + 2 + head];
    float ub = dec_max(ubenc[head]) + ald;          // >= max over incoming e
    ub = (ub >= 0.f) ? ub : NEG_SLOPE * ub;

    float s = 0.f, ax = 0.f, ay = 0.f;

    int sC[4], sN[4];
    float eC[4], eN[4];
    float2 hC[4], hN[4];

    // prologue: block(beg) fully loaded, ssrc of block(beg+4)
#pragma unroll
    for (int k = 0; k < 4; k++) {
        const int idx = beg + k;
        const int sv = ssrc[idx];                    // padded array: safe read
        sC[k] = (idx < end) ? sv : 0;
    }
#pragma unroll
    for (int k = 0; k < 4; k++) {
        const int idx = beg + k;
        const float als = AL[(size_t)sC[k] * 4 + head];
        eC[k] = (idx < end) ? als : -__builtin_inff();
        hC[k] = *(const float2*)(H + (size_t)sC[k] * 128 + 2 * lane);
    }
#pragma unroll
    for (int k = 0; k < 4; k++) {
        const int idx = beg + 4 + k;
        const int sv = ssrc[idx];
        sN[k] = (idx < end) ? sv : 0;
    }

    for (int j = beg; j < end; j += 4) {
        int sNN[4];
#pragma unroll
        for (int k = 0; k < 4; k++) {
            const int idx = j + 8 + k;
            const int sv = ssrc[idx];
            sNN[k] = (idx < end) ? sv : 0;
        }
#pragma unroll
        for (int k = 0; k < 4; k++) {
            const int idx = j + 4 + k;
            const float als = AL[(size_t)sN[k] * 4 + head];
            eN[k] = (idx < end) ? als : -__builtin_inff();
            hN[k] = *(const float2*)(H + (size_t)sN[k] * 128 + 2 * lane);
        }
#pragma unroll
        for (int k = 0; k < 4; k++) {
            float t = eC[k] + ald;                  // -inf for masked slots
            t = (t >= 0.f) ? t : NEG_SLOPE * t;
            const float p = __expf(t - ub);         // exp(-inf)=0 for masked
            s += p;
            ax = fmaf(p, hC[k].x, ax);
            ay = fmaf(p, hC[k].y, ay);
        }
#pragma unroll
        for (int k = 0; k < 4; k++) { sN[k] = sNN[k]; eC[k] = eN[k]; hC[k] = hN[k]; }
    }

    const float inv = 1.f / s;                      // s > 0 (self loop)
    float o0 = ax * inv, o1 = ay * inv;

    if (mode == 0) {
        o0 += bias[2 * lane]; o1 += bias[2 * lane + 1];
        o0 = (o0 > 0.f) ? o0 : (__expf(o0) - 1.f);  // ELU
        o1 = (o1 > 0.f) ? o1 : (__expf(o1) - 1.f);
        ((float2*)out)[(size_t)n * 64 + lane] = make_float2(o0, o1);
    } else {
        const float p0 = __shfl_xor(o0, 32, 64);
        const float p1 = __shfl_xor(o1, 32, 64);
        if (lane < 32) {
            const float r0 = 0.5f * (o0 + p0) + bias[2 * lane];
            const float r1 = 0.5f * (o1 + p1) + bias[2 * lane + 1];
            ((float2*)out)[(size_t)n * 32 + lane] = make_float2(r0, r1);
        }
    }
}

// ---------------------------------------------------------------------------
extern "C" void kernel_launch(void* const* d_in, const int* in_sizes, int n_in,
                              void* d_out, int out_size, void* d_ws, size_t ws_size,
                              hipStream_t stream)
{
    const float* x   = (const float*)d_in[0];
    const int*   eix = (const int*)d_in[1];   // [2, E] int32
    const float* W1  = (const float*)d_in[2];
    const float* as1 = (const float*)d_in[3];
    const float* ad1 = (const float*)d_in[4];
    const float* b1  = (const float*)d_in[5];
    const float* W2  = (const float*)d_in[6];
    const float* as2 = (const float*)d_in[7];
    const float* ad2 = (const float*)d_in[8];
    const float* b2  = (const float*)d_in[9];
    float* out = (float*)d_out;

    const int N = in_sizes[0] / 128;
    const int E = in_sizes[1] / 2;
    const int Etot = E + N;
    const int* esrc = eix;
    const int* edst = eix + E;

    // workspace layout (~113 MB)
    char* p = (char*)d_ws;
    float*    h      = (float*)p;    p += (size_t)N * 128 * 4;
    float*    y1     = (float*)p;    p += (size_t)N * 128 * 4;
    float*    al     = (float*)p;    p += (size_t)N * 4 * 4;
    int*      cnt    = (int*)p;      p += (size_t)N * 4;
    unsigned* ub     = (unsigned*)p; p += 8 * 4;          // ub[0..1] L1, ub[2..3] L2
    int*      indptr = (int*)p;      p += (size_t)(N + 1) * 4;
    int*      cursor = (int*)p;      p += (size_t)N * 4;
    int*      bsum   = (int*)p;      p += 1024 * 4;
    int*      ssrc   = (int*)p;      p += (size_t)(Etot + 16) * 4;  // +pad for pipeline

    hipMemsetAsync(cnt, 0, (size_t)N * 4 + 32, stream);   // cnt + ub

    // --- CSR by destination (shared by both layers) ---
    {
        const int eblocks = (Etot + 255) / 256;
        count_kernel<<<eblocks, 256, 0, stream>>>(edst, cnt, E, N);
        const int B = (N + SCAN_B - 1) / SCAN_B;
        scan1_kernel<<<B, SCAN_B, 0, stream>>>(cnt, indptr, bsum, N);
        scan2_kernel<<<1, 1024, 0, stream>>>(bsum, B);
        scan3_kernel<<<B, SCAN_B, 0, stream>>>(indptr, cnt, bsum, cursor, N, Etot);
        scatter_kernel<<<eblocks, 256, 0, stream>>>(esrc, edst, cursor, ssrc, E, N);
    }

    const int ggrid = (N + 127) / 128;                       // 128 rows/block
    const int ablocks = (int)(((size_t)N * 64 + 255) / 256); // 1 wave per node

    // --- Layer 1 ---
    gemm_al_kernel<<<ggrid, 512, 0, stream>>>(x, W1, as1, ad1, h, al, N);
    almax_kernel<<<256, 256, 0, stream>>>(al, ub, N);
    aggregate_kernel<<<ablocks, 256, 0, stream>>>(h, al, indptr, ssrc, ub, b1, y1, N, 0);

    // --- Layer 2 ---
    gemm_al_kernel<<<ggrid, 512, 0, stream>>>(y1, W2, as2, ad2, h, al, N);
    almax_kernel<<<256, 256, 0, stream>>>(al, ub + 2, N);
    aggregate_kernel<<<ablocks, 256, 0, stream>>>(h, al, indptr, ssrc, ub + 2, b2, out, N, 1);
}